// Round 11
// baseline (7515.040 us; speedup 1.0000x reference)
//
#include <hip/hip_runtime.h>
#include <hip/hip_fp16.h>

#define BB 32
#define LL 512
#define HH 1024
#define NL 4
#define RS 8     // h ring slots per layer
#define RSHIFT 3
#define TPL 32   // blocks per layer
#define CPB 32   // cols per block
#define TAGM 0x0001000100010001ULL   // LSB of each f16 in an 8B quantum

typedef unsigned long long ull;
typedef _Float16 f16x8 __attribute__((ext_vector_type(8)));
typedef float    f32x4 __attribute__((ext_vector_type(4)));

__device__ __forceinline__ f16x8 cvt8(const float* __restrict__ p) {
  f32x4 lo = *reinterpret_cast<const f32x4*>(p);
  f32x4 hi = *reinterpret_cast<const f32x4*>(p + 4);
  f16x8 r;
#pragma unroll
  for (int e = 0; e < 4; ++e) { r[e] = (_Float16)lo[e]; r[e + 4] = (_Float16)hi[e]; }
  return r;
}

// Fast tier: plain cacheable 16B loads from hL. Producer wrote hL with plain
// stores -> lines are DIRTY in the producer XCD's L2; same-XCD consumers hit
// them fresh and coarse (no fabric). L1 staleness is washed by >128KB/step
// churn and caught by tags regardless.
__device__ __forceinline__ bool try_plain_row16(f16x8* __restrict__ o,
                                                const _Float16* __restrict__ base,
                                                ull wantv) {
  f16x8 tmp[16];
#pragma unroll
  for (int j = 0; j < 16; ++j)
    tmp[j] = *reinterpret_cast<const f16x8*>(base + j * 32);
  ull bad = 0;
#pragma unroll
  for (int j = 0; j < 16; ++j) {
    union { f16x8 v; ull u[2]; } c; c.v = tmp[j];
    bad |= ((c.u[0] ^ wantv) | (c.u[1] ^ wantv)) & TAGM;
  }
  if (bad) return false;
#pragma unroll
  for (int j = 0; j < 16; ++j) o[j] = tmp[j];
  return true;
}

// Safety net (round-6-proven): 8B relaxed agent atomic spin on the MALL
// master copy. Always correct, always terminates.
__device__ __forceinline__ void spin_load_row16(f16x8* __restrict__ o,
                                                const _Float16* __restrict__ base,
                                                ull wantv) {
  const ull* p = reinterpret_cast<const ull*>(base);
  ull q0[16], q1[16];
#pragma unroll
  for (int j = 0; j < 16; ++j) {
    q0[j] = __hip_atomic_load(p + j * 8,     __ATOMIC_RELAXED, __HIP_MEMORY_SCOPE_AGENT);
    q1[j] = __hip_atomic_load(p + j * 8 + 1, __ATOMIC_RELAXED, __HIP_MEMORY_SCOPE_AGENT);
  }
  for (;;) {
    ull bad = 0;
#pragma unroll
    for (int j = 0; j < 16; ++j)
      bad |= ((q0[j] ^ wantv) | (q1[j] ^ wantv)) & TAGM;
    if (bad == 0) break;
#pragma unroll
    for (int j = 0; j < 16; ++j) {
      q0[j] = __hip_atomic_load(p + j * 8,     __ATOMIC_RELAXED, __HIP_MEMORY_SCOPE_AGENT);
      q1[j] = __hip_atomic_load(p + j * 8 + 1, __ATOMIC_RELAXED, __HIP_MEMORY_SCOPE_AGENT);
    }
  }
#pragma unroll
  for (int j = 0; j < 16; ++j) {
    union { ull u[2]; f16x8 v; } c;
    c.u[0] = q0[j]; c.u[1] = q1[j];
    o[j] = c.v;
  }
}

// Persistent pipeline, 128 active blocks: layer = blockIdx&7 (XCD-locality
// heuristic only; tags + MALL fallback keep correctness placement-free).
// Block: 32 cols, weights in VGPRs; waves 0-1 input GEMM, waves 2-3 hidden.
// Hidden operand (critical path) rides the local L2 via hL; cross-layer input
// operand rides the MALL via hM.
__global__ __launch_bounds__(256, 1) void rnn_persist(
    const float* __restrict__ x,   // [B][L][H] f32
    const float* __restrict__ h0,  // [NL][B][H] f32
    const float* __restrict__ WI,  // [NL][H][H] f32
    const float* __restrict__ BI,  // [NL][H]
    const float* __restrict__ WH,  // [NL][H][H] f32
    const float* __restrict__ BH,  // [NL][H]
    float* __restrict__ out,       // [B][L][H] f32 ++ hfinal [NL][B][H]
    _Float16* __restrict__ hL,     // [NL][RS][B][H] local-L2 copy (plain stores)
    _Float16* __restrict__ hM,     // [NL][RS][B][H] MALL master (atomic stores)
    unsigned* __restrict__ pflag) {// [NL][TPL]: t+1 after step t
  const int l = blockIdx.x & 7;
  if (l >= NL) return;
  const int tile = blockIdx.x >> 3;
  const int c0   = tile * CPB;
  const int tid  = threadIdx.x;
  const int w    = tid >> 6;
  const int lane = tid & 63;
  const int crow = lane & 15;
  const int kgrp = lane >> 4;
  const int kofs = (w & 1) * 512;

  // ---- weight fragments -> registers (once) ----
  f16x8 wfrag[2][16];
  {
    const float* Wb = (w < 2 ? WI : WH) + (size_t)l * HH * HH;
#pragma unroll
    for (int ct = 0; ct < 2; ++ct) {
      const float* wr = Wb + (size_t)(c0 + ct * 16 + crow) * HH + kofs + kgrp * 8;
#pragma unroll
      for (int j = 0; j < 16; ++j) wfrag[ct][j] = cvt8(wr + j * 32);
    }
  }

  // ---- epilogue: tid<128 -> (row rb2, 8 cols at c8) = one 16B store ----
  const int rb2 = tid >> 2;          // 0..31 for tid<128
  const int c8  = (tid & 3) * 8;
  float bias8[8];
#pragma unroll
  for (int j = 0; j < 8; ++j)
    bias8[j] = BI[l * HH + c0 + c8 + j] + BH[l * HH + c0 + c8 + j];

  __shared__ float red[2][4][2][16][34];

  for (int t = 0; t < LL; ++t) {
    const ull wantI = ((t >> RSHIFT) & 1) ? TAGM : 0ULL;        // gen t (input)
    const ull wantH = (((t - 1) >> RSHIFT) & 1) ? TAGM : 0ULL;  // gen t-1 (hidden)

    // ---------- flag gates (round-8-proven), s_sleep(4) backoff ----------
    if (tid < 96) {
      const int g  = tid >> 5;
      const int Lt = tid & 31;
      if (g == 0) {
        if (t > 0)
          while (__hip_atomic_load(&pflag[l * TPL + Lt], __ATOMIC_RELAXED,
                                   __HIP_MEMORY_SCOPE_AGENT) < (unsigned)t)
            __builtin_amdgcn_s_sleep(4);
      } else if (g == 1) {
        if (l > 0)
          while (__hip_atomic_load(&pflag[(l - 1) * TPL + Lt], __ATOMIC_RELAXED,
                                   __HIP_MEMORY_SCOPE_AGENT) < (unsigned)(t + 1))
            __builtin_amdgcn_s_sleep(4);
      } else {
        if (l < NL - 1 && t >= RS)
          while (__hip_atomic_load(&pflag[(l + 1) * TPL + Lt], __ATOMIC_RELAXED,
                                   __HIP_MEMORY_SCOPE_AGENT) < (unsigned)(t - (RS - 1)))
            __builtin_amdgcn_s_sleep(4);
      }
    }
    __syncthreads();

    // ---------- phased operand load + MFMA ----------
    f32x4 acc[2][2];
#pragma unroll
    for (int ct = 0; ct < 2; ++ct)
#pragma unroll
      for (int rt = 0; rt < 2; ++rt) acc[ct][rt] = (f32x4){0.f, 0.f, 0.f, 0.f};

#pragma unroll
    for (int rt = 0; rt < 2; ++rt) {
      f16x8 af[16];
      const size_t rowoff = (size_t)(rt * 16 + crow) * HH + kofs + kgrp * 8;
      if (w < 2) {            // input operand: x (l==0) or h_{l-1} gen t via MALL
        if (l == 0) {
          const float* r = x + ((size_t)(rt * 16 + crow) * LL + t) * HH + kofs + kgrp * 8;
#pragma unroll
          for (int j = 0; j < 16; ++j) af[j] = cvt8(r + j * 32);
        } else {
          const size_t slot = (size_t)((l - 1) * RS + (t & (RS - 1))) * BB * HH;
          spin_load_row16(af, hM + slot + rowoff, wantI);
        }
      } else {                // hidden operand: h0 (t==0) or own h gen t-1 via LOCAL L2
        if (t == 0) {
          const float* r = h0 + ((size_t)l * BB + rt * 16 + crow) * HH + kofs + kgrp * 8;
#pragma unroll
          for (int j = 0; j < 16; ++j) af[j] = cvt8(r + j * 32);
        } else {
          const size_t slot = (size_t)(l * RS + ((t - 1) & (RS - 1))) * BB * HH;
          if (!try_plain_row16(af, hL + slot + rowoff, wantH))
            spin_load_row16(af, hM + slot + rowoff, wantH);
        }
      }
#pragma unroll
      for (int j = 0; j < 16; ++j)
#pragma unroll
        for (int ct = 0; ct < 2; ++ct)
          acc[ct][rt] = __builtin_amdgcn_mfma_f32_16x16x32_f16(af[j], wfrag[ct][j],
                                                               acc[ct][rt], 0, 0, 0);
    }

    // ---------- cross-wave k-reduce via LDS (ping-pong) ----------
    const int pp = t & 1;
#pragma unroll
    for (int ct = 0; ct < 2; ++ct)
#pragma unroll
      for (int rt = 0; rt < 2; ++rt)
#pragma unroll
        for (int r = 0; r < 4; ++r)
          red[pp][w][rt][kgrp * 4 + r][ct * 16 + crow] = acc[ct][rt][r];
    __syncthreads();

    float v[8];
    if (tid < 128) {
#pragma unroll
      for (int j = 0; j < 8; ++j) {
        float s = bias8[j];
#pragma unroll
        for (int w2 = 0; w2 < 4; ++w2) s += red[pp][w2][rb2 >> 4][rb2 & 15][c8 + j];
        v[j] = tanhf(s);
      }
      // pack 8 f16 with per-8B LSB tags
      union { _Float16 h[8]; ull u[2]; f16x8 vv; } pk;
#pragma unroll
      for (int j = 0; j < 8; ++j) pk.h[j] = (_Float16)v[j];
      const ull tg = ((t >> RSHIFT) & 1) ? TAGM : 0ULL;
      pk.u[0] = (pk.u[0] & ~TAGM) | tg;
      pk.u[1] = (pk.u[1] & ~TAGM) | tg;
      const size_t off = ((size_t)(l * RS + (t & (RS - 1))) * BB + rb2) * HH + c0 + c8;
      *reinterpret_cast<f16x8*>(hL + off) = pk.vv;   // plain -> dirty in local L2
      __hip_atomic_store(reinterpret_cast<ull*>(hM + off), pk.u[0],
                         __ATOMIC_RELAXED, __HIP_MEMORY_SCOPE_AGENT);
      __hip_atomic_store(reinterpret_cast<ull*>(hM + off) + 1, pk.u[1],
                         __ATOMIC_RELAXED, __HIP_MEMORY_SCOPE_AGENT);
    }
    // Drain: all waves wait vmcnt(0) entering the barrier -> hL in L2, hM at MALL.
    __syncthreads();

    // ---------- publish progress ----------
    if (tid == 0)
      __hip_atomic_store(&pflag[l * TPL + tile], (unsigned)(t + 1), __ATOMIC_RELAXED,
                         __HIP_MEMORY_SCOPE_AGENT);

    // ---------- out stores (off critical path) ----------
    if (tid < 128) {
      if (l == NL - 1) {
        f32x4 o0 = {v[0], v[1], v[2], v[3]}, o1 = {v[4], v[5], v[6], v[7]};
        float* po = out + ((size_t)rb2 * LL + t) * HH + c0 + c8;
        __builtin_nontemporal_store(o0, reinterpret_cast<f32x4*>(po));
        __builtin_nontemporal_store(o1, reinterpret_cast<f32x4*>(po + 4));
      }
      if (t == LL - 1) {
        f32x4 o0 = {v[0], v[1], v[2], v[3]}, o1 = {v[4], v[5], v[6], v[7]};
        float* pf = out + (size_t)BB * LL * HH + ((size_t)l * BB + rb2) * HH + c0 + c8;
        __builtin_nontemporal_store(o0, reinterpret_cast<f32x4*>(pf));
        __builtin_nontemporal_store(o1, reinterpret_cast<f32x4*>(pf + 4));
      }
    }
  }
}

extern "C" void kernel_launch(void* const* d_in, const int* in_sizes, int n_in,
                              void* d_out, int out_size, void* d_ws, size_t ws_size,
                              hipStream_t stream) {
  const float* x  = (const float*)d_in[0];
  const float* h0 = (const float*)d_in[1];
  const float* WI = (const float*)d_in[2];
  const float* BI = (const float*)d_in[3];
  const float* WH = (const float*)d_in[4];
  const float* BH = (const float*)d_in[5];
  float* out = (float*)d_out;

  const size_t hbytes = (size_t)NL * RS * BB * HH * sizeof(_Float16);  // 2 MB
  _Float16* hL = (_Float16*)d_ws;
  _Float16* hM = (_Float16*)((char*)d_ws + hbytes);
  unsigned* pflag = (unsigned*)((char*)d_ws + 2 * hbytes);

  // 0xFF: every f16 LSB=1 -> invalid for generation-0 (parity 0) consumers.
  hipMemsetAsync(d_ws, 0xFF, 2 * hbytes, stream);
  hipMemsetAsync(pflag, 0, (size_t)NL * TPL * sizeof(unsigned), stream);
  rnn_persist<<<256, 256, 0, stream>>>(x, h0, WI, BI, WH, BH, out, hL, hM, pflag);
}